// Round 1
// 249.589 us; speedup vs baseline: 1.0232x; 1.0232x over previous
//
#include <hip/hip_runtime.h>
#include <stdint.h>

// B=32, Cin=128, T=4096, K=4, Cout=256, ks=7, pad=3
// v2: 256-t conv tile (halves W L2 traffic, 256-VGPR budget, no spill risk);
// fold reads w directly (drop k_wt), computes alpha in-block (drop k_alpha).

#define TP 4102   // 4096 + 6 halo rows (3 each side), zero-padded

// workspace offsets (bytes)
#define XT_OFF     0u            // bf16 x planes [b][g=16][TP][8ci]  -> 33,603,584 B
#define WEFF_OFF   33603584u     // bf16 folded W, wave-fragment tiled -> 14,680,064 B
#define POOLED_OFF 48283648u     // fp32 [32][128]
#define BEFF_OFF   48300032u     // fp32 [32][256]

typedef short short8 __attribute__((ext_vector_type(8)));
typedef float f32x4 __attribute__((ext_vector_type(4)));

__device__ __forceinline__ unsigned short f2bf(float f) {
  unsigned int u = __builtin_bit_cast(unsigned int, f);
  u += 0x7fffu + ((u >> 16) & 1u);   // RNE
  return (unsigned short)(u >> 16);
}

// ---------------------------------------------------------------------------
// Kernel 1: x [b][ci][t] fp32 -> bf16 planes xt[b][g][3+t][8ci] (halo zeroed),
// plus pooled[b][ci] partial sums (atomicAdd onto memset-zeroed buffer).
// ---------------------------------------------------------------------------
__global__ __launch_bounds__(256) void k_transpose_pool(
    const float* __restrict__ x, unsigned short* __restrict__ xt,
    float* __restrict__ pooled) {
  __shared__ __align__(16) unsigned short xs[128 * 136]; // [ci][t]
  __shared__ float pbuf[128 * 33];
  int blk = blockIdx.x;
  int b = blk >> 5, tc = blk & 31;
  int t0 = tc << 7;
  int tid = threadIdx.x;
  int lane32 = tid & 31, grp8 = tid >> 5;

  #pragma unroll
  for (int i = 0; i < 16; ++i) {
    int ci = i * 8 + grp8;
    const float4 v = *(const float4*)(x + (size_t)(b * 128 + ci) * 4096 + t0 + lane32 * 4);
    unsigned short h0 = f2bf(v.x), h1 = f2bf(v.y), h2 = f2bf(v.z), h3 = f2bf(v.w);
    uint2 pk;
    pk.x = (unsigned)h0 | ((unsigned)h1 << 16);
    pk.y = (unsigned)h2 | ((unsigned)h3 << 16);
    *(uint2*)(&xs[ci * 136 + lane32 * 4]) = pk;
    pbuf[ci * 33 + lane32] = v.x + v.y + v.z + v.w;
  }
  __syncthreads();
  if (tid < 128) {
    float s = 0.f;
    #pragma unroll
    for (int l = 0; l < 32; ++l) s += pbuf[tid * 33 + l];
    atomicAdd(&pooled[b * 128 + tid], s);
  }
  #pragma unroll
  for (int it = 0; it < 8; ++it) {
    int idx = it * 256 + tid;      // 2048 = 128 tr x 16 g
    int tr = idx & 127, g = idx >> 7;
    unsigned short h[8];
    #pragma unroll
    for (int u = 0; u < 8; ++u) h[u] = xs[(g * 8 + u) * 136 + tr];
    uint4 o;
    o.x = (unsigned)h[0] | ((unsigned)h[1] << 16);
    o.y = (unsigned)h[2] | ((unsigned)h[3] << 16);
    o.z = (unsigned)h[4] | ((unsigned)h[5] << 16);
    o.w = (unsigned)h[6] | ((unsigned)h[7] << 16);
    *(uint4*)(xt + ((size_t)(b * 16 + g) * TP + 3 + t0 + tr) * 8) = o;
  }
  uint4 z; z.x = z.y = z.z = z.w = 0;
  if (tc == 0 && tid < 64) {
    int g = tid >> 2, pr = tid & 3;
    if (pr < 3) *(uint4*)(xt + ((size_t)(b * 16 + g) * TP + pr) * 8) = z;
  }
  if (tc == 31 && tid < 64) {
    int g = tid >> 2, pr = tid & 3;
    if (pr < 3) *(uint4*)(xt + ((size_t)(b * 16 + g) * TP + 4099 + pr) * 8) = z;
  }
}

// ---------------------------------------------------------------------------
// Kernel 2 (fold): computes alpha in-block (redundant, cheap), bias_eff
// (block 0), and folded bf16 weights in wave-fragment order. Reads w ONCE
// (b-loop inside thread), native [k][cout][ci][s] layout.
//   weff_short8[((bcb*28 + step)*8 + cblk)*64 + q*16 + n16], bcb=b*2+cb,
//   cout = cb*128 + cblk*16 + n16, ci = half*64 + (kk*4+q)*8 + j,
//   step = (s*2+half)*2 + kk.
// ---------------------------------------------------------------------------
__global__ __launch_bounds__(256) void k_fold(
    const float* __restrict__ w, const float* __restrict__ pooled,
    const float* __restrict__ rw, const float* __restrict__ rb,
    const float* __restrict__ bias, unsigned short* __restrict__ weff,
    float* __restrict__ bias_eff) {
  __shared__ float al[32][4];
  int tid = threadIdx.x;
  // --- alpha logits: 128 threads = 32 b x 4 k, serial length-128 dot ---
  if (tid < 128) {
    int b = tid >> 2, k = tid & 3;
    const float* pp = pooled + b * 128;
    const float* rwk = rw + k * 128;
    float s = rb[k];
    #pragma unroll 8
    for (int j = 0; j < 128; ++j) s += pp[j] * (1.0f / 4096.0f) * rwk[j];
    al[b][k] = s;
  }
  __syncthreads();
  if (tid < 32) {
    float l0 = al[tid][0], l1 = al[tid][1], l2 = al[tid][2], l3 = al[tid][3];
    float m = fmaxf(fmaxf(l0, l1), fmaxf(l2, l3));
    float e0 = __expf(l0 - m), e1 = __expf(l1 - m);
    float e2 = __expf(l2 - m), e3 = __expf(l3 - m);
    float inv = 1.0f / (e0 + e1 + e2 + e3);
    al[tid][0] = e0 * inv; al[tid][1] = e1 * inv;
    al[tid][2] = e2 * inv; al[tid][3] = e3 * inv;
  }
  __syncthreads();
  // --- bias_eff: block 0 only ---
  if (blockIdx.x == 0) {
    #pragma unroll
    for (int b = 0; b < 32; ++b) {
      float s = 0.f;
      #pragma unroll
      for (int k = 0; k < 4; ++k) s += al[b][k] * bias[k * 256 + tid];
      bias_eff[b * 256 + tid] = s;
    }
  }
  // --- fold: one thread per weff fragment position, loop over 32 b ---
  int gid = blockIdx.x * 256 + tid;   // 28672 = 2 cb * 28 step * 8 cblk * 64
  int cb = gid / 14336;
  int r = gid - cb * 14336;
  int step = r >> 9;
  int cblk = (r >> 6) & 7;
  int lpos = r & 63;
  int q = lpos >> 4, n16 = lpos & 15;
  int kk = step & 1, half = (step >> 1) & 1, s7 = step >> 2;
  int cout = cb * 128 + cblk * 16 + n16;
  int ci0 = half * 64 + (kk * 4 + q) * 8;
  float wv[4][8];
  #pragma unroll
  for (int k = 0; k < 4; ++k) {
    const float* src = w + ((size_t)(k * 256 + cout) * 128 + ci0) * 7 + s7;
    #pragma unroll
    for (int j = 0; j < 8; ++j) wv[k][j] = src[j * 7];
  }
  unsigned short* dst =
      weff + (((size_t)(cb * 28 + step) * 8 + cblk) * 64 + lpos) * 8;
  #pragma unroll 4
  for (int b = 0; b < 32; ++b) {
    float a0 = al[b][0], a1 = al[b][1], a2 = al[b][2], a3 = al[b][3];
    unsigned short h[8];
    #pragma unroll
    for (int j = 0; j < 8; ++j)
      h[j] = f2bf(a0 * wv[0][j] + a1 * wv[1][j] + a2 * wv[2][j] + a3 * wv[3][j]);
    uint4 o;
    o.x = (unsigned)h[0] | ((unsigned)h[1] << 16);
    o.y = (unsigned)h[2] | ((unsigned)h[3] << 16);
    o.z = (unsigned)h[4] | ((unsigned)h[5] << 16);
    o.w = (unsigned)h[6] | ((unsigned)h[7] << 16);
    *(uint4*)(dst + (size_t)b * 229376) = o;   // b stride: 2*28*8*64*8 ushorts
  }
}

// ---------------------------------------------------------------------------
// Kernel 3: conv as implicit GEMM, barrier-free K-loop, 256-t tile.
// Block = 128 cout x 256 t for one (b,cb). x tile in LDS [g][262 rows][8ci];
// W streamed global->VGPR (L2-resident), one-step-ahead prefetch.
// 4 waves 2x2 (wm: cout-64, wn: t-128), each 64x128 via 4x8 mfma 16x16x32.
// ---------------------------------------------------------------------------
__global__ __launch_bounds__(256, 2) void k_conv(
    const unsigned short* __restrict__ xt, const unsigned short* __restrict__ weff,
    const float* __restrict__ bias_eff, float* __restrict__ out) {
  __shared__ __align__(16) unsigned short xs[16 * 262 * 8];  // 67,072 B -> 2 blk/CU
  int blk = blockIdx.x;            // 1024 = 32 b * 2 cb * 16 tb
  int b = blk >> 5, cb = (blk >> 4) & 1, tb = blk & 15;
  int bcb = b * 2 + cb;
  int tid = threadIdx.x;
  int wave = tid >> 6, lane = tid & 63;
  int q = lane >> 4, n16 = lane & 15;
  int wm = wave & 1, wn = wave >> 1;
  int t00 = tb << 8;

  // stage x tile: 262 rows x 16 g-planes; one full-wave-coalesced 4KB run per g
  const unsigned short* xtb = xt + (size_t)b * 16 * TP * 8;
  #pragma unroll
  for (int g = 0; g < 16; ++g) {
    *(uint4*)(&xs[((size_t)g * 262 + tid) * 8]) =
        *(const uint4*)(xtb + ((size_t)g * TP + t00 + tid) * 8);
  }
  if (tid < 128) {
    int g = tid >> 3, r8 = tid & 7;
    if (r8 < 6) {
      int row = 256 + r8;
      *(uint4*)(&xs[((size_t)g * 262 + row) * 8]) =
          *(const uint4*)(xtb + ((size_t)g * TP + t00 + row) * 8);
    }
  }
  __syncthreads();

  f32x4 acc[4][8];
  #pragma unroll
  for (int mi = 0; mi < 4; ++mi)
    #pragma unroll
    for (int ni = 0; ni < 8; ++ni)
      acc[mi][ni] = (f32x4){0.f, 0.f, 0.f, 0.f};

  // W fragment pointer: short8 units; step*512 + mi*64 offsets are linear.
  const short8* wfrag = (const short8*)weff + (size_t)bcb * 14336 + (wm * 4) * 64 + lane;

  short8 av[4];
  #pragma unroll
  for (int mi = 0; mi < 4; ++mi) av[mi] = wfrag[mi * 64];

  #pragma unroll 2
  for (int step = 0; step < 28; ++step) {
    int s = step >> 2, half = (step >> 1) & 1, kk = step & 1;
    short8 avn[4];
    if (step < 27) {
      #pragma unroll
      for (int mi = 0; mi < 4; ++mi)
        avn[mi] = wfrag[(step + 1) * 512 + mi * 64];
    }
    short8 bv[8];
    int prow = (half * 8 + kk * 4 + q) * 262 + s;
    #pragma unroll
    for (int ni = 0; ni < 8; ++ni) {
      int tt = wn * 128 + ni * 16 + n16;
      bv[ni] = *(const short8*)(&xs[(size_t)(prow + tt) * 8]);
    }
    #pragma unroll
    for (int mi = 0; mi < 4; ++mi)
      #pragma unroll
      for (int ni = 0; ni < 8; ++ni)
        acc[mi][ni] = __builtin_amdgcn_mfma_f32_16x16x32_bf16(
            av[mi], bv[ni], acc[mi][ni], 0, 0, 0);
    #pragma unroll
    for (int mi = 0; mi < 4; ++mi) av[mi] = avn[mi];
  }

  // epilogue: D layout col(lane&15)=t, row(q*4+r)=cout
  int crow0 = b * 256 + cb * 128;
  #pragma unroll
  for (int mi = 0; mi < 4; ++mi) {
    #pragma unroll
    for (int r = 0; r < 4; ++r) {
      int c = wm * 64 + mi * 16 + q * 4 + r;
      float bb = bias_eff[crow0 + c];
      float* orow = out + (size_t)(crow0 + c) * 4096 + t00;
      #pragma unroll
      for (int ni = 0; ni < 8; ++ni)
        orow[wn * 128 + ni * 16 + n16] = acc[mi][ni][r] + bb;
    }
  }
}

extern "C" void kernel_launch(void* const* d_in, const int* in_sizes, int n_in,
                              void* d_out, int out_size, void* d_ws, size_t ws_size,
                              hipStream_t stream) {
  const float* x    = (const float*)d_in[0];
  const float* w    = (const float*)d_in[1];
  const float* bias = (const float*)d_in[2];
  const float* rw   = (const float*)d_in[3];
  const float* rb   = (const float*)d_in[4];
  float* out = (float*)d_out;
  char* ws = (char*)d_ws;
  unsigned short* xt   = (unsigned short*)(ws + XT_OFF);
  unsigned short* weff = (unsigned short*)(ws + WEFF_OFF);
  float* pooled        = (float*)(ws + POOLED_OFF);
  float* bias_eff      = (float*)(ws + BEFF_OFF);

  hipMemsetAsync(pooled, 0, 32 * 128 * sizeof(float), stream);
  hipLaunchKernelGGL(k_transpose_pool, dim3(1024), dim3(256), 0, stream, x, xt, pooled);
  hipLaunchKernelGGL(k_fold, dim3(112), dim3(256), 0, stream,
                     w, pooled, rw, rb, bias, weff, bias_eff);
  hipLaunchKernelGGL(k_conv, dim3(1024), dim3(256), 0, stream, xt, weff, bias_eff, out);
}

// Round 3
// 239.153 us; speedup vs baseline: 1.0679x; 1.0436x over previous
//
#include <hip/hip_runtime.h>
#include <stdint.h>

// B=32, Cin=128, T=4096, K=4, Cout=256, ks=7, pad=3
// v4: non-cooperative 3-kernel pipeline (coop launch fails under harness
// graph capture -> v3 never ran). k_pool: exact fp32 pooled sums (no
// atomics/memset). k_fold: round-1-proven alpha+bias_eff+weff fold.
// k_conv2: stages x fp32->bf16 conv-ready LDS tile directly (no xt
// round-trip) and runs both cout halves on the same tile.

// workspace offsets (bytes)
#define WEFF_OFF   0u          // bf16 folded W [b][cb][step][cblk][lpos][8] -> 14,680,064 B
#define POOLED_OFF 14680064u   // fp32 [32][128]
#define BEFF_OFF   14696448u   // fp32 [32][256]

typedef short short8 __attribute__((ext_vector_type(8)));
typedef float f32x4 __attribute__((ext_vector_type(4)));

__device__ __forceinline__ unsigned short f2bf(float f) {
  unsigned int u = __builtin_bit_cast(unsigned int, f);
  u += 0x7fffu + ((u >> 16) & 1u);   // RNE
  return (unsigned short)(u >> 16);
}

// ---------------------------------------------------------------------------
// Kernel 1: pooled[b][ci] = sum_t x[b][ci][t]  (exact fp32, one block per row)
// ---------------------------------------------------------------------------
__global__ __launch_bounds__(256) void k_pool(const float* __restrict__ x,
                                              float* __restrict__ pooled) {
  __shared__ float ws4[4];
  int row = blockIdx.x;                       // b*128 + ci, 4096 rows
  const float* src = x + (size_t)row * 4096 + threadIdx.x * 16;
  float s = 0.f;
  #pragma unroll
  for (int i = 0; i < 4; ++i) {
    float4 v = *(const float4*)(src + i * 4);
    s += (v.x + v.y) + (v.z + v.w);
  }
  #pragma unroll
  for (int off = 32; off > 0; off >>= 1) s += __shfl_down(s, off);
  int lane = threadIdx.x & 63, wv = threadIdx.x >> 6;
  if (lane == 0) ws4[wv] = s;
  __syncthreads();
  if (threadIdx.x == 0) pooled[row] = (ws4[0] + ws4[1]) + (ws4[2] + ws4[3]);
}

// ---------------------------------------------------------------------------
// Kernel 2 (fold): alpha in-block (redundant, cheap), bias_eff (block 0),
// folded bf16 weights in wave-fragment order. Reads w ONCE (b-loop inside
// thread), native [k][cout][ci][s] layout.
//   weff_short8[((bcb*28 + step)*8 + cblk)*64 + q*16 + n16], bcb=b*2+cb,
//   cout = cb*128 + cblk*16 + n16, ci = half*64 + (kk*4+q)*8 + j,
//   step = (s*2+half)*2 + kk.
// ---------------------------------------------------------------------------
__global__ __launch_bounds__(256) void k_fold(
    const float* __restrict__ w, const float* __restrict__ pooled,
    const float* __restrict__ rw, const float* __restrict__ rb,
    const float* __restrict__ bias, unsigned short* __restrict__ weff,
    float* __restrict__ bias_eff) {
  __shared__ float al[32][4];
  int tid = threadIdx.x;
  // --- alpha logits: 128 threads = 32 b x 4 k, serial length-128 dot ---
  if (tid < 128) {
    int b = tid >> 2, k = tid & 3;
    const float* pp = pooled + b * 128;
    const float* rwk = rw + k * 128;
    float s = rb[k];
    #pragma unroll 8
    for (int j = 0; j < 128; ++j) s += pp[j] * (1.0f / 4096.0f) * rwk[j];
    al[b][k] = s;
  }
  __syncthreads();
  if (tid < 32) {
    float l0 = al[tid][0], l1 = al[tid][1], l2 = al[tid][2], l3 = al[tid][3];
    float m = fmaxf(fmaxf(l0, l1), fmaxf(l2, l3));
    float e0 = __expf(l0 - m), e1 = __expf(l1 - m);
    float e2 = __expf(l2 - m), e3 = __expf(l3 - m);
    float inv = 1.0f / (e0 + e1 + e2 + e3);
    al[tid][0] = e0 * inv; al[tid][1] = e1 * inv;
    al[tid][2] = e2 * inv; al[tid][3] = e3 * inv;
  }
  __syncthreads();
  // --- bias_eff: block 0 only ---
  if (blockIdx.x == 0) {
    #pragma unroll
    for (int b = 0; b < 32; ++b) {
      float s = 0.f;
      #pragma unroll
      for (int k = 0; k < 4; ++k) s += al[b][k] * bias[k * 256 + tid];
      bias_eff[b * 256 + tid] = s;
    }
  }
  // --- fold: one thread per weff fragment position, loop over 32 b ---
  int gid = blockIdx.x * 256 + tid;   // 28672 = 2 cb * 28 step * 8 cblk * 64
  int cb = gid / 14336;
  int r = gid - cb * 14336;
  int step = r >> 9;
  int cblk = (r >> 6) & 7;
  int lpos = r & 63;
  int q = lpos >> 4, n16 = lpos & 15;
  int kk = step & 1, half = (step >> 1) & 1, s7 = step >> 2;
  int cout = cb * 128 + cblk * 16 + n16;
  int ci0 = half * 64 + (kk * 4 + q) * 8;
  float wv[4][8];
  #pragma unroll
  for (int k = 0; k < 4; ++k) {
    const float* src = w + ((size_t)(k * 256 + cout) * 128 + ci0) * 7 + s7;
    #pragma unroll
    for (int j = 0; j < 8; ++j) wv[k][j] = src[j * 7];
  }
  unsigned short* dst =
      weff + (((size_t)(cb * 28 + step) * 8 + cblk) * 64 + lpos) * 8;
  #pragma unroll 4
  for (int b = 0; b < 32; ++b) {
    float a0 = al[b][0], a1 = al[b][1], a2 = al[b][2], a3 = al[b][3];
    unsigned short h[8];
    #pragma unroll
    for (int j = 0; j < 8; ++j)
      h[j] = f2bf(a0 * wv[0][j] + a1 * wv[1][j] + a2 * wv[2][j] + a3 * wv[3][j]);
    uint4 o;
    o.x = (unsigned)h[0] | ((unsigned)h[1] << 16);
    o.y = (unsigned)h[2] | ((unsigned)h[3] << 16);
    o.z = (unsigned)h[4] | ((unsigned)h[5] << 16);
    o.w = (unsigned)h[6] | ((unsigned)h[7] << 16);
    *(uint4*)(dst + (size_t)b * 229376) = o;   // b stride: 2*28*8*64*8 ushorts
  }
}

// ---------------------------------------------------------------------------
// Kernel 3: conv. Block = one (b,tb): stages x fp32->bf16 LDS tile
// [g=16][262 rows][8ci] directly from x (halo zero-padded), then implicit-GEMM
// conv for BOTH cout halves reusing the tile. 4 waves 2x2 (wm: cout-64,
// wn: t-128), each 64x128 via 4x8 mfma 16x16x32. W streamed global->VGPR
// with one-step-ahead prefetch. XCD swizzle clusters same-b blocks.
// ---------------------------------------------------------------------------
__global__ __launch_bounds__(256, 2) void k_conv2(
    const float* __restrict__ x, const unsigned short* __restrict__ weff,
    const float* __restrict__ bias_eff, float* __restrict__ out) {
  __shared__ __align__(16) unsigned short xs[16 * 262 * 8];  // 67,072 B
  int phys = blockIdx.x;                         // 512 = 32 b * 16 tb
  int logical = (phys & 7) * 64 + (phys >> 3);   // bijective: same-b per XCD
  int b = logical >> 4, tb = logical & 15;
  int tid = threadIdx.x;
  int t00 = tb << 8;

  // ---- stage x tile: rows hold t = t00-3+row, zero outside [0,4096) ----
  {
    const float* xbase = x + (size_t)b * 128 * 4096;
    int xrow = t00 - 3 + tid;
    bool valid = (unsigned)xrow < 4096u;
    #pragma unroll
    for (int g = 0; g < 16; ++g) {
      float f[8];
      #pragma unroll
      for (int u = 0; u < 8; ++u)
        f[u] = valid ? xbase[(size_t)(g * 8 + u) * 4096 + xrow] : 0.f;
      uint4 o;
      o.x = (unsigned)f2bf(f[0]) | ((unsigned)f2bf(f[1]) << 16);
      o.y = (unsigned)f2bf(f[2]) | ((unsigned)f2bf(f[3]) << 16);
      o.z = (unsigned)f2bf(f[4]) | ((unsigned)f2bf(f[5]) << 16);
      o.w = (unsigned)f2bf(f[6]) | ((unsigned)f2bf(f[7]) << 16);
      *(uint4*)(&xs[(g * 262 + tid) * 8]) = o;
    }
    if (tid < 128) {
      int g = tid >> 3, r8 = tid & 7;
      if (r8 < 6) {
        int row2 = 256 + r8;
        int xrow2 = t00 - 3 + row2;
        bool v2 = (unsigned)xrow2 < 4096u;
        float f[8];
        #pragma unroll
        for (int u = 0; u < 8; ++u)
          f[u] = v2 ? xbase[(size_t)(g * 8 + u) * 4096 + xrow2] : 0.f;
        uint4 o;
        o.x = (unsigned)f2bf(f[0]) | ((unsigned)f2bf(f[1]) << 16);
        o.y = (unsigned)f2bf(f[2]) | ((unsigned)f2bf(f[3]) << 16);
        o.z = (unsigned)f2bf(f[4]) | ((unsigned)f2bf(f[5]) << 16);
        o.w = (unsigned)f2bf(f[6]) | ((unsigned)f2bf(f[7]) << 16);
        *(uint4*)(&xs[(g * 262 + row2) * 8]) = o;
      }
    }
  }
  __syncthreads();

  // ---- conv: two cb passes over the same x tile ----
  int wave = tid >> 6, lane = tid & 63;
  int q = lane >> 4, n16 = lane & 15;
  int wm = wave & 1, wn = wave >> 1;
  const short8* wb8 = (const short8*)weff + (size_t)b * 28672;

  for (int cb = 0; cb < 2; ++cb) {
    f32x4 acc[4][8];
    #pragma unroll
    for (int mi = 0; mi < 4; ++mi)
      #pragma unroll
      for (int ni = 0; ni < 8; ++ni)
        acc[mi][ni] = (f32x4){0.f, 0.f, 0.f, 0.f};

    const short8* wfrag = wb8 + (cb * 224 + wm * 4) * 64 + lane;
    short8 av[4];
    #pragma unroll
    for (int mi = 0; mi < 4; ++mi) av[mi] = wfrag[mi * 64];

    #pragma unroll 2
    for (int step = 0; step < 28; ++step) {
      int s = step >> 2, half = (step >> 1) & 1, kk = step & 1;
      short8 avn[4];
      if (step < 27) {
        #pragma unroll
        for (int mi = 0; mi < 4; ++mi)
          avn[mi] = wfrag[(step + 1) * 512 + mi * 64];
      }
      short8 bv[8];
      int prow = (half * 8 + kk * 4 + q) * 262 + s;
      #pragma unroll
      for (int ni = 0; ni < 8; ++ni) {
        int tt = wn * 128 + ni * 16 + n16;
        bv[ni] = *(const short8*)(&xs[(size_t)(prow + tt) * 8]);
      }
      #pragma unroll
      for (int mi = 0; mi < 4; ++mi)
        #pragma unroll
        for (int ni = 0; ni < 8; ++ni)
          acc[mi][ni] = __builtin_amdgcn_mfma_f32_16x16x32_bf16(
              av[mi], bv[ni], acc[mi][ni], 0, 0, 0);
      #pragma unroll
      for (int mi = 0; mi < 4; ++mi) av[mi] = avn[mi];
    }

    // epilogue: D layout col(lane&15)=t, row(q*4+r)=cout
    int crow0 = b * 256 + cb * 128;
    #pragma unroll
    for (int mi = 0; mi < 4; ++mi) {
      #pragma unroll
      for (int r = 0; r < 4; ++r) {
        int c = wm * 64 + mi * 16 + q * 4 + r;
        float bb = bias_eff[crow0 + c];
        float* orow = out + (size_t)(crow0 + c) * 4096 + t00;
        #pragma unroll
        for (int ni = 0; ni < 8; ++ni)
          orow[wn * 128 + ni * 16 + n16] = acc[mi][ni][r] + bb;
      }
    }
  }
}

extern "C" void kernel_launch(void* const* d_in, const int* in_sizes, int n_in,
                              void* d_out, int out_size, void* d_ws, size_t ws_size,
                              hipStream_t stream) {
  const float* x    = (const float*)d_in[0];
  const float* w    = (const float*)d_in[1];
  const float* bias = (const float*)d_in[2];
  const float* rw   = (const float*)d_in[3];
  const float* rb   = (const float*)d_in[4];
  float* out = (float*)d_out;
  char* ws = (char*)d_ws;
  unsigned short* weff = (unsigned short*)(ws + WEFF_OFF);
  float* pooled        = (float*)(ws + POOLED_OFF);
  float* bias_eff      = (float*)(ws + BEFF_OFF);

  hipLaunchKernelGGL(k_pool,  dim3(4096), dim3(256), 0, stream, x, pooled);
  hipLaunchKernelGGL(k_fold,  dim3(112),  dim3(256), 0, stream,
                     w, pooled, rw, rb, bias, weff, bias_eff);
  hipLaunchKernelGGL(k_conv2, dim3(512),  dim3(256), 0, stream,
                     x, weff, bias_eff, out);
}